// Round 1
// baseline (756.226 us; speedup 1.0000x reference)
//
#include <hip/hip_runtime.h>

// Problem constants
constexpr int B = 64, L = 256, D = 1024;
constexpr int BD = B * D;          // 65536, row stride of q/p viewed as [L*B, D]
constexpr float EPS = 1e-6f;

// GEMM tiling: 128x128 block tile, 8x8 micro tile, K-step 16, 256 threads
constexpr int BM = 128, BN = 128, BK = 16;

// ---------------------------------------------------------------------------
// Kernel: G = WF^T @ WF   (TN gemm, M=N=K=1024)  G[k1,k2] = sum_e WF[e,k1]*WF[e,k2]
// ---------------------------------------------------------------------------
__global__ __launch_bounds__(256) void k_gram(const float* __restrict__ WF,
                                              float* __restrict__ G) {
    __shared__ alignas(16) float As[BK][BM + 4];
    __shared__ alignas(16) float Bs[BK][BN + 4];
    const int t = threadIdx.x;
    const int k1b = blockIdx.y * BM, k2b = blockIdx.x * BN;
    const int tx = t & 15, ty = t >> 4;
    float acc[8][8] = {};
    for (int e0 = 0; e0 < D; e0 += BK) {
        #pragma unroll
        for (int r = 0; r < 2; ++r) {
            int g = t + r * 256;               // 512 float4 granules per tile
            int kk = g >> 5, c = g & 31;       // 16 rows x 32 col-granules
            float4 a = *(const float4*)(WF + (e0 + kk) * D + k1b + 4 * c);
            *(float4*)&As[kk][4 * c] = a;
            float4 b = *(const float4*)(WF + (e0 + kk) * D + k2b + 4 * c);
            *(float4*)&Bs[kk][4 * c] = b;
        }
        __syncthreads();
        #pragma unroll
        for (int ee = 0; ee < BK; ++ee) {
            float a[8], b[8];
            *(float4*)&a[0] = *(const float4*)&As[ee][ty * 8];
            *(float4*)&a[4] = *(const float4*)&As[ee][ty * 8 + 4];
            *(float4*)&b[0] = *(const float4*)&Bs[ee][tx * 8];
            *(float4*)&b[4] = *(const float4*)&Bs[ee][tx * 8 + 4];
            #pragma unroll
            for (int i = 0; i < 8; ++i)
                #pragma unroll
                for (int j = 0; j < 8; ++j) acc[i][j] += a[i] * b[j];
        }
        __syncthreads();
    }
    #pragma unroll
    for (int i = 0; i < 8; ++i)
        #pragma unroll
        for (int j = 0; j < 8; j += 4)
            *(float4*)(G + (k1b + ty * 8 + i) * D + k2b + tx * 8 + j) = *(float4*)&acc[i][j];
}

// ---------------------------------------------------------------------------
// Kernel: T = A @ G  (NN gemm) A = q viewed [16384,1024] row m=(l*B+b)
// ---------------------------------------------------------------------------
__global__ __launch_bounds__(256) void k_qG(const float* __restrict__ A,
                                            const float* __restrict__ G,
                                            float* __restrict__ T) {
    __shared__ alignas(16) float As[BK][BM + 4];   // transposed: As[k][m]
    __shared__ alignas(16) float Bs[BK][BN + 4];
    const int t = threadIdx.x;
    const int mb = blockIdx.y * BM, nb = blockIdx.x * BN;
    const int tx = t & 15, ty = t >> 4;
    float acc[8][8] = {};
    for (int k0 = 0; k0 < D; k0 += BK) {
        #pragma unroll
        for (int r = 0; r < 2; ++r) {
            int g = t + r * 256;
            int mr = g >> 2, kc = g & 3;           // 128 rows x 4 k-granules
            float4 a = *(const float4*)(A + (mb + mr) * D + k0 + 4 * kc);
            As[4 * kc + 0][mr] = a.x; As[4 * kc + 1][mr] = a.y;
            As[4 * kc + 2][mr] = a.z; As[4 * kc + 3][mr] = a.w;
            int kk = g >> 5, c = g & 31;
            float4 b = *(const float4*)(G + (k0 + kk) * D + nb + 4 * c);
            *(float4*)&Bs[kk][4 * c] = b;
        }
        __syncthreads();
        #pragma unroll
        for (int ee = 0; ee < BK; ++ee) {
            float a[8], b[8];
            *(float4*)&a[0] = *(const float4*)&As[ee][ty * 8];
            *(float4*)&a[4] = *(const float4*)&As[ee][ty * 8 + 4];
            *(float4*)&b[0] = *(const float4*)&Bs[ee][tx * 8];
            *(float4*)&b[4] = *(const float4*)&Bs[ee][tx * 8 + 4];
            #pragma unroll
            for (int i = 0; i < 8; ++i)
                #pragma unroll
                for (int j = 0; j < 8; ++j) acc[i][j] += a[i] * b[j];
        }
        __syncthreads();
    }
    #pragma unroll
    for (int i = 0; i < 8; ++i)
        #pragma unroll
        for (int j = 0; j < 8; j += 4)
            *(float4*)(T + (mb + ty * 8 + i) * D + nb + tx * 8 + j) = *(float4*)&acc[i][j];
}

// ---------------------------------------------------------------------------
// Kernel: E[b] = T_b @ P_b^T (NT, batched). Rows of T_b/P_b at (row*BD + b*D).
// E[b*65536 + q*256 + p]
// ---------------------------------------------------------------------------
__global__ __launch_bounds__(256) void k_e(const float* __restrict__ T,
                                           const float* __restrict__ P,
                                           float* __restrict__ E) {
    __shared__ alignas(16) float As[BK][BM + 4];   // As[d][q]
    __shared__ alignas(16) float Bs[BK][BN + 4];   // Bs[d][p]
    const int t = threadIdx.x;
    const int b = blockIdx.z;
    const int qb = blockIdx.y * BM, pb = blockIdx.x * BN;
    const int tx = t & 15, ty = t >> 4;
    float acc[8][8] = {};
    for (int d0 = 0; d0 < D; d0 += BK) {
        #pragma unroll
        for (int r = 0; r < 2; ++r) {
            int g = t + r * 256;
            int mr = g >> 2, kc = g & 3;
            float4 a = *(const float4*)(T + (qb + mr) * BD + b * D + d0 + 4 * kc);
            As[4 * kc + 0][mr] = a.x; As[4 * kc + 1][mr] = a.y;
            As[4 * kc + 2][mr] = a.z; As[4 * kc + 3][mr] = a.w;
            float4 c = *(const float4*)(P + (pb + mr) * BD + b * D + d0 + 4 * kc);
            Bs[4 * kc + 0][mr] = c.x; Bs[4 * kc + 1][mr] = c.y;
            Bs[4 * kc + 2][mr] = c.z; Bs[4 * kc + 3][mr] = c.w;
        }
        __syncthreads();
        #pragma unroll
        for (int ee = 0; ee < BK; ++ee) {
            float a[8], b[8];
            *(float4*)&a[0] = *(const float4*)&As[ee][ty * 8];
            *(float4*)&a[4] = *(const float4*)&As[ee][ty * 8 + 4];
            *(float4*)&b[0] = *(const float4*)&Bs[ee][tx * 8];
            *(float4*)&b[4] = *(const float4*)&Bs[ee][tx * 8 + 4];
            #pragma unroll
            for (int i = 0; i < 8; ++i)
                #pragma unroll
                for (int j = 0; j < 8; ++j) acc[i][j] += a[i] * b[j];
        }
        __syncthreads();
    }
    float* eb = E + b * (L * L);
    #pragma unroll
    for (int i = 0; i < 8; ++i)
        #pragma unroll
        for (int j = 0; j < 8; j += 4)
            *(float4*)(eb + (qb + ty * 8 + i) * L + pb + tx * 8 + j) = *(float4*)&acc[i][j];
}

// ---------------------------------------------------------------------------
// Row stats for softmax_j (over p, per (b,q) row). One wave per row.
// x = e*m (m = qm[b,q]*pm[b,p]); max over ALL p of x; sum of exp(x-max)*m.
// ---------------------------------------------------------------------------
__global__ __launch_bounds__(256) void k_rowstats_j(const float* __restrict__ E,
                                                    const int* __restrict__ qm,
                                                    const int* __restrict__ pm,
                                                    float* __restrict__ rmax,
                                                    float* __restrict__ rsum) {
    const int wid = threadIdx.x >> 6, lane = threadIdx.x & 63;
    const int row = blockIdx.x * 4 + wid;        // row = b*256 + q
    const int b = row >> 8, q = row & 255;
    const float qmv = (float)qm[b * L + q];
    const float* er = E + row * L;
    float x[4], msk[4];
    float mx = -1e30f;
    #pragma unroll
    for (int i = 0; i < 4; ++i) {
        int pp = lane + 64 * i;
        msk[i] = qmv * (float)pm[b * L + pp];
        x[i] = er[pp] * msk[i];
        mx = fmaxf(mx, x[i]);
    }
    #pragma unroll
    for (int o = 32; o; o >>= 1) mx = fmaxf(mx, __shfl_xor(mx, o));
    float s = 0.f;
    #pragma unroll
    for (int i = 0; i < 4; ++i) s += msk[i] * __expf(x[i] - mx);
    #pragma unroll
    for (int o = 32; o; o >>= 1) s += __shfl_xor(s, o);
    if (lane == 0) { rmax[row] = mx; rsum[row] = s; }
}

// ---------------------------------------------------------------------------
// Row stats for softmax_i (over q, per (b,p)). Block per b, thread = p,
// online max/sum over q with coalesced reads of E rows.
// ---------------------------------------------------------------------------
__global__ __launch_bounds__(256) void k_rowstats_i(const float* __restrict__ E,
                                                    const int* __restrict__ qm,
                                                    const int* __restrict__ pm,
                                                    float* __restrict__ rmax,
                                                    float* __restrict__ rsum) {
    const int b = blockIdx.x, p = threadIdx.x;
    const float pmv = (float)pm[b * L + p];
    const float* eb = E + b * (L * L);
    float m = -1e30f, s = 0.f;
    for (int q = 0; q < L; ++q) {
        float mm = pmv * (float)qm[b * L + q];
        float x = eb[q * L + p] * mm;
        float mn = fmaxf(m, x);
        s = s * __expf(m - mn) + mm * __expf(x - mn);
        m = mn;
    }
    rmax[b * L + p] = m; rsum[b * L + p] = s;
}

// ---------------------------------------------------------------------------
// colsum_j[b,p] = sum_q softmax_j[b,q,p].  Block per b, thread = p, loop q.
// ---------------------------------------------------------------------------
__global__ __launch_bounds__(256) void k_colsum_j(const float* __restrict__ E,
                                                  const int* __restrict__ qm,
                                                  const int* __restrict__ pm,
                                                  const float* __restrict__ rmaxj,
                                                  const float* __restrict__ rsumj,
                                                  float* __restrict__ colj) {
    const int b = blockIdx.x, p = threadIdx.x;
    const float pmv = (float)pm[b * L + p];
    const float* eb = E + b * (L * L);
    float acc = 0.f;
    for (int q = 0; q < L; ++q) {
        float mm = pmv * (float)qm[b * L + q];
        float x = eb[q * L + p] * mm;
        float inv = 1.0f / (rsumj[b * L + q] + EPS);
        acc += mm * __expf(x - rmaxj[b * L + q]) * inv;
    }
    colj[b * L + p] = acc;
}

// ---------------------------------------------------------------------------
// colsum_i[b,q] = sum_p softmax_i[b,p,q]. One wave per (b,q) row.
// ---------------------------------------------------------------------------
__global__ __launch_bounds__(256) void k_colsum_i(const float* __restrict__ E,
                                                  const int* __restrict__ qm,
                                                  const int* __restrict__ pm,
                                                  const float* __restrict__ rmaxi,
                                                  const float* __restrict__ rsumi,
                                                  float* __restrict__ coli) {
    const int wid = threadIdx.x >> 6, lane = threadIdx.x & 63;
    const int row = blockIdx.x * 4 + wid;        // row = b*256 + q
    const int b = row >> 8, q = row & 255;
    const float qmv = (float)qm[b * L + q];
    const float* er = E + row * L;
    float acc = 0.f;
    #pragma unroll
    for (int i = 0; i < 4; ++i) {
        int pp = lane + 64 * i;
        float mm = qmv * (float)pm[b * L + pp];
        float x = er[pp] * mm;
        acc += mm * __expf(x - rmaxi[b * L + pp]) / (rsumi[b * L + pp] + EPS);
    }
    #pragma unroll
    for (int o = 32; o; o >>= 1) acc += __shfl_xor(acc, o);
    if (lane == 0) coli[row] = acc;
}

// ---------------------------------------------------------------------------
// Per-batch sums over L: sum_l q, sum_l p, sum_p colj*p, sum_q coli*q.
// grid = B * (D/256); thread handles one (b,d).
// ---------------------------------------------------------------------------
__global__ __launch_bounds__(256) void k_sums(const float* __restrict__ Q,
                                              const float* __restrict__ P,
                                              const float* __restrict__ colj,
                                              const float* __restrict__ coli,
                                              float* __restrict__ sumq,
                                              float* __restrict__ sump,
                                              float* __restrict__ sumbeta,
                                              float* __restrict__ sumalpha) {
    const int b = blockIdx.x >> 2;
    const int d = (blockIdx.x & 3) * 256 + threadIdx.x;
    float aq = 0.f, ap = 0.f, ab = 0.f, aa = 0.f;
    for (int l = 0; l < L; ++l) {
        float qv = Q[l * BD + b * D + d];
        float pv = P[l * BD + b * D + d];
        aq += qv; ap += pv;
        ab += colj[b * L + l] * pv;
        aa += coli[b * L + l] * qv;
    }
    sumq[b * D + d] = aq;  sump[b * D + d] = ap;
    sumbeta[b * D + d] = ab; sumalpha[b * D + d] = aa;
}

// ---------------------------------------------------------------------------
// g1[k] = sum_e WG[e,k]*WH[0,e];  g2[k] = sum_e WG[e,k]*WH[0,D+e];  k<2D
// ---------------------------------------------------------------------------
__global__ __launch_bounds__(256) void k_g(const float* __restrict__ WG,
                                           const float* __restrict__ WH,
                                           float* __restrict__ g1,
                                           float* __restrict__ g2) {
    const int k = blockIdx.x * 256 + threadIdx.x;   // 0..2047
    float a = 0.f, c = 0.f;
    for (int e = 0; e < D; ++e) {
        float w = WG[e * (2 * D) + k];
        a += w * WH[e];
        c += w * WH[D + e];
    }
    g1[k] = a; g2[k] = c;
}

// ---------------------------------------------------------------------------
// out[b] = <sumq,g1[:D]> + <sumbeta,g1[D:]> + <sump,g2[:D]> + <sumalpha,g2[D:]>
// ---------------------------------------------------------------------------
__global__ __launch_bounds__(256) void k_final(const float* __restrict__ sumq,
                                               const float* __restrict__ sump,
                                               const float* __restrict__ sumbeta,
                                               const float* __restrict__ sumalpha,
                                               const float* __restrict__ g1,
                                               const float* __restrict__ g2,
                                               float* __restrict__ out) {
    const int b = blockIdx.x, t = threadIdx.x;
    float acc = 0.f;
    for (int d = t; d < D; d += 256) {
        acc += sumq[b * D + d] * g1[d] + sumbeta[b * D + d] * g1[D + d] +
               sump[b * D + d] * g2[d] + sumalpha[b * D + d] * g2[D + d];
    }
    #pragma unroll
    for (int o = 32; o; o >>= 1) acc += __shfl_xor(acc, o);
    __shared__ float red[4];
    const int wid = t >> 6, lane = t & 63;
    if (lane == 0) red[wid] = acc;
    __syncthreads();
    if (t == 0) out[b] = red[0] + red[1] + red[2] + red[3];
}

extern "C" void kernel_launch(void* const* d_in, const int* in_sizes, int n_in,
                              void* d_out, int out_size, void* d_ws, size_t ws_size,
                              hipStream_t stream) {
    const float* q  = (const float*)d_in[0];
    const float* p  = (const float*)d_in[1];
    const int*   qm = (const int*)d_in[2];
    const int*   pm = (const int*)d_in[3];
    const float* WF = (const float*)d_in[4];
    const float* WG = (const float*)d_in[5];
    const float* WH = (const float*)d_in[6];
    float* out = (float*)d_out;

    // Workspace layout (~85.4 MB of f32)
    float* ws = (float*)d_ws;
    float* G      = ws;                    // 1M
    float* T      = G + (1 << 20);         // 16M
    float* E      = T + (16 << 20);        // 4M
    float* rmj    = E + (4 << 20);         // 16K each below
    float* rsj    = rmj + B * L;
    float* rmi    = rsj + B * L;
    float* rsi    = rmi + B * L;
    float* colj   = rsi + B * L;
    float* coli   = colj + B * L;
    float* sumq   = coli + B * L;          // 64K each below
    float* sump   = sumq + B * D;
    float* sumb   = sump + B * D;
    float* suma   = sumb + B * D;
    float* g1     = suma + B * D;          // 2K each
    float* g2     = g1 + 2 * D;

    // 1. Gram matrix G = WF^T WF
    k_gram<<<dim3(D / BN, D / BM), 256, 0, stream>>>(WF, G);
    // 2. T = q_flat @ G   (M = L*B = 16384)
    k_qG<<<dim3(D / BN, (L * B) / BM), 256, 0, stream>>>(q, G, T);
    // 3. E[b] = T_b @ p_b^T
    k_e<<<dim3(L / BN, L / BM, B), 256, 0, stream>>>(T, p, E);
    // 4. softmax stats (both directions)
    k_rowstats_j<<<(B * L) / 4, 256, 0, stream>>>(E, qm, pm, rmj, rsj);
    k_rowstats_i<<<B, 256, 0, stream>>>(E, qm, pm, rmi, rsi);
    // 5. column sums of softmax matrices
    k_colsum_j<<<B, 256, 0, stream>>>(E, qm, pm, rmj, rsj, colj);
    k_colsum_i<<<(B * L) / 4, 256, 0, stream>>>(E, qm, pm, rmi, rsi, coli);
    // 6. per-batch sums over L
    k_sums<<<B * 4, 256, 0, stream>>>(q, p, colj, coli, sumq, sump, sumb, suma);
    // 7. folded WG/WH vectors
    k_g<<<(2 * D) / 256, 256, 0, stream>>>(WG, WH, g1, g2);
    // 8. final dot products
    k_final<<<B, 256, 0, stream>>>(sumq, sump, sumb, suma, g1, g2, out);
}

// Round 2
// 372.502 us; speedup vs baseline: 2.0301x; 2.0301x over previous
//
#include <hip/hip_runtime.h>

using f32x4  = __attribute__((ext_vector_type(4))) float;
using bf16x8 = __attribute__((ext_vector_type(8))) short;

constexpr int B = 64, L = 256, D = 1024;
constexpr int BD = B * D;          // 65536
constexpr float EPS = 1e-6f;

// ---------------------------------------------------------------------------
// helpers
// ---------------------------------------------------------------------------
__device__ __forceinline__ short f2bf(float x) {           // RTN-even f32->bf16
    unsigned u = __float_as_uint(x);
    unsigned r = u + 0x7FFFu + ((u >> 16) & 1u);
    return (short)(r >> 16);
}
__device__ __forceinline__ float bf2f(short h) {
    return __uint_as_float(((unsigned)(unsigned short)h) << 16);
}
__device__ __forceinline__ void gload_lds16(const void* g, void* l) {
    __builtin_amdgcn_global_load_lds((const __attribute__((address_space(1))) void*)g,
                                     (__attribute__((address_space(3))) void*)l,
                                     16, 0, 0);
}

// ---------------------------------------------------------------------------
// fp32 -> (hi,lo) bf16 split, elementwise, 8 elems/thread. grid*256*8 == n.
// ---------------------------------------------------------------------------
__global__ __launch_bounds__(256) void k_cvt(const float* __restrict__ x,
                                             short* __restrict__ xh,
                                             short* __restrict__ xl) {
    const int i = blockIdx.x * 256 + threadIdx.x;
    const float4* xp = (const float4*)x;
    float4 a = xp[2 * i], b = xp[2 * i + 1];
    float v[8] = {a.x, a.y, a.z, a.w, b.x, b.y, b.z, b.w};
    union { short s[8]; int4 q; } H, Lo;
    #pragma unroll
    for (int k = 0; k < 8; ++k) {
        H.s[k] = f2bf(v[k]);
        Lo.s[k] = f2bf(v[k] - bf2f(H.s[k]));
    }
    ((int4*)xh)[i] = H.q;
    ((int4*)xl)[i] = Lo.q;
}

// ---------------------------------------------------------------------------
// WF [D][D] fp32 -> transposed hi/lo bf16 (Y[k1][e] = WF[e][k1])
// ---------------------------------------------------------------------------
__global__ __launch_bounds__(256) void k_cvt_t(const float* __restrict__ X,
                                               short* __restrict__ Yh,
                                               short* __restrict__ Yl) {
    __shared__ float tile[32][33];
    const int t = threadIdx.x;
    const int rt = blockIdx.y, ct = blockIdx.x;
    const int r = t >> 3, c4 = (t & 7) * 4;
    float4 v = *(const float4*)(X + (long)(rt * 32 + r) * D + ct * 32 + c4);
    tile[r][c4] = v.x; tile[r][c4 + 1] = v.y; tile[r][c4 + 2] = v.z; tile[r][c4 + 3] = v.w;
    __syncthreads();
    float w0 = tile[c4 + 0][r], w1 = tile[c4 + 1][r];
    float w2 = tile[c4 + 2][r], w3 = tile[c4 + 3][r];
    long o = (long)(ct * 32 + r) * D + rt * 32 + c4;
    short4 h, l;
    h.x = f2bf(w0); l.x = f2bf(w0 - bf2f(h.x));
    h.y = f2bf(w1); l.y = f2bf(w1 - bf2f(h.y));
    h.z = f2bf(w2); l.z = f2bf(w2 - bf2f(h.z));
    h.w = f2bf(w3); l.w = f2bf(w3 - bf2f(h.w));
    *(short4*)(Yh + o) = h;
    *(short4*)(Yl + o) = l;
}

// ---------------------------------------------------------------------------
// Split-bf16 NT GEMM: C = (Ah+Al)(Bh+Bl)^T, dropping Al*Bl (rel err ~2^-16).
// Both operands K-major (rows of length K). 128x128 tile, BK=32, 4 waves,
// per-wave 64x64 (4x4 frags of 16x16x32). LDS: 2 bufs x 4 tiles x 8KB = 64KB,
// 2-phase prefetch via global_load_lds (linear dest + pre-swizzled source:
// granule (r,g) -> slot r*4 + (g ^ ((r>>1)&3)) -> 2-way (free) ds_read banks).
// Output: split hi/lo bf16 (split_out=1) or fp32.
// ---------------------------------------------------------------------------
__global__ __launch_bounds__(256, 2) void k_gemm_nt(
    const short* __restrict__ Ah, const short* __restrict__ Al, long strideA, long batchA,
    const short* __restrict__ Bh, const short* __restrict__ Bl, long strideB, long batchB,
    int K, int bx, int per_batch, int split_out,
    short* __restrict__ Ch, short* __restrict__ Cl, float* __restrict__ Cf,
    int ldC, long batchC)
{
    __shared__ __align__(16) short lds_s[32768];   // 64 KB
    const int t = threadIdx.x, lane = t & 63, w = t >> 6;
    const int wm = w >> 1, wn = w & 1;

    // XCD-bijective swizzle (all grids divisible by 8)
    const int lin = blockIdx.x;
    const int chunk = gridDim.x >> 3;
    const int swz = (lin & 7) * chunk + (lin >> 3);
    const int z = swz / per_batch;
    const int r0 = swz % per_batch;
    const int bm = r0 / bx, bn = r0 % bx;
    const int mb = bm * 128, nb = bn * 128;

    // stage pointers: wave w owns tile w (0=Ah,1=Al,2=Bh,3=Bl)
    const char* mat; long rstride; int row0;
    if (w == 0)      { mat = (const char*)Ah + batchA * z; rstride = strideA; row0 = mb; }
    else if (w == 1) { mat = (const char*)Al + batchA * z; rstride = strideA; row0 = mb; }
    else if (w == 2) { mat = (const char*)Bh + batchB * z; rstride = strideB; row0 = nb; }
    else             { mat = (const char*)Bl + batchB * z; rstride = strideB; row0 = nb; }
    const char* sp[8];
    #pragma unroll
    for (int i = 0; i < 8; ++i) {
        int rr = i * 16 + (lane >> 2);
        int g = (lane & 3) ^ ((rr >> 1) & 3);        // inverse-swizzled source granule
        sp[i] = mat + (long)(row0 + rr) * rstride + g * 16;
    }

    // swizzled fragment byte offsets within an 8KB tile (loop-invariant)
    int aoff[4], boff[4];
    #pragma unroll
    for (int f = 0; f < 4; ++f) {
        int ra = wm * 64 + f * 16 + (lane & 15);
        aoff[f] = (ra * 4 + ((lane >> 4) ^ ((ra >> 1) & 3))) * 16;
        int rb = wn * 64 + f * 16 + (lane & 15);
        boff[f] = (rb * 4 + ((lane >> 4) ^ ((rb >> 1) & 3))) * 16;
    }

    f32x4 acc[4][4] = {};
    const int NT = K >> 5;

    {   // prologue stage of buf 0
        short* dst = &lds_s[w * 4096];
        #pragma unroll
        for (int i = 0; i < 8; ++i) gload_lds16(sp[i], dst + i * 512);
    }
    __syncthreads();   // drains vmcnt + barrier

    int cur = 0;
    for (int kt = 0; kt < NT; ++kt) {
        if (kt + 1 < NT) {   // issue next-tile loads before compute
            short* dst = &lds_s[(cur ^ 1) * 16384 + w * 4096];
            long ko = (long)(kt + 1) * 64;
            #pragma unroll
            for (int i = 0; i < 8; ++i) gload_lds16(sp[i] + ko, dst + i * 512);
        }
        const char* lb = (const char*)lds_s + cur * 32768;
        bf16x8 ah[4], al[4], bh[4], bl[4];
        #pragma unroll
        for (int f = 0; f < 4; ++f) {
            ah[f] = *(const bf16x8*)(lb + aoff[f]);
            al[f] = *(const bf16x8*)(lb + 8192  + aoff[f]);
            bh[f] = *(const bf16x8*)(lb + 16384 + boff[f]);
            bl[f] = *(const bf16x8*)(lb + 24576 + boff[f]);
        }
        #pragma unroll
        for (int i = 0; i < 4; ++i)
            #pragma unroll
            for (int j = 0; j < 4; ++j) {
                acc[i][j] = __builtin_amdgcn_mfma_f32_16x16x32_bf16(ah[i], bh[j], acc[i][j], 0, 0, 0);
                acc[i][j] = __builtin_amdgcn_mfma_f32_16x16x32_bf16(ah[i], bl[j], acc[i][j], 0, 0, 0);
                acc[i][j] = __builtin_amdgcn_mfma_f32_16x16x32_bf16(al[i], bh[j], acc[i][j], 0, 0, 0);
            }
        __syncthreads();   // drains just-issued stage loads + barrier
        cur ^= 1;
    }

    // epilogue: C/D frag mapping col=lane&15, row=(lane>>4)*4+reg  [m89]
    const long zC = batchC * z;
    #pragma unroll
    for (int i = 0; i < 4; ++i)
        #pragma unroll
        for (int j = 0; j < 4; ++j) {
            int row = mb + wm * 64 + i * 16 + (lane >> 4) * 4;
            int col = nb + wn * 64 + j * 16 + (lane & 15);
            #pragma unroll
            for (int rr = 0; rr < 4; ++rr) {
                float v = acc[i][j][rr];
                long idx = zC + (long)(row + rr) * ldC + col;
                if (split_out) {
                    short h = f2bf(v);
                    Ch[idx] = h;
                    Cl[idx] = f2bf(v - bf2f(h));
                } else {
                    Cf[idx] = v;
                }
            }
        }
}

// ---------------------------------------------------------------------------
// softmax stats / colsums / sums / fold / final (unchanged from R1 — verified)
// ---------------------------------------------------------------------------
__global__ __launch_bounds__(256) void k_rowstats_j(const float* __restrict__ E,
                                                    const int* __restrict__ qm,
                                                    const int* __restrict__ pm,
                                                    float* __restrict__ rmax,
                                                    float* __restrict__ rsum) {
    const int wid = threadIdx.x >> 6, lane = threadIdx.x & 63;
    const int row = blockIdx.x * 4 + wid;        // row = b*256 + q
    const int b = row >> 8, q = row & 255;
    const float qmv = (float)qm[b * L + q];
    const float* er = E + row * L;
    float x[4], msk[4];
    float mx = -1e30f;
    #pragma unroll
    for (int i = 0; i < 4; ++i) {
        int pp = lane + 64 * i;
        msk[i] = qmv * (float)pm[b * L + pp];
        x[i] = er[pp] * msk[i];
        mx = fmaxf(mx, x[i]);
    }
    #pragma unroll
    for (int o = 32; o; o >>= 1) mx = fmaxf(mx, __shfl_xor(mx, o));
    float s = 0.f;
    #pragma unroll
    for (int i = 0; i < 4; ++i) s += msk[i] * __expf(x[i] - mx);
    #pragma unroll
    for (int o = 32; o; o >>= 1) s += __shfl_xor(s, o);
    if (lane == 0) { rmax[row] = mx; rsum[row] = s; }
}

__global__ __launch_bounds__(256) void k_rowstats_i(const float* __restrict__ E,
                                                    const int* __restrict__ qm,
                                                    const int* __restrict__ pm,
                                                    float* __restrict__ rmax,
                                                    float* __restrict__ rsum) {
    const int b = blockIdx.x, p = threadIdx.x;
    const float pmv = (float)pm[b * L + p];
    const float* eb = E + b * (L * L);
    float m = -1e30f, s = 0.f;
    for (int q = 0; q < L; ++q) {
        float mm = pmv * (float)qm[b * L + q];
        float x = eb[q * L + p] * mm;
        float mn = fmaxf(m, x);
        s = s * __expf(m - mn) + mm * __expf(x - mn);
        m = mn;
    }
    rmax[b * L + p] = m; rsum[b * L + p] = s;
}

__global__ __launch_bounds__(256) void k_colsum_j(const float* __restrict__ E,
                                                  const int* __restrict__ qm,
                                                  const int* __restrict__ pm,
                                                  const float* __restrict__ rmaxj,
                                                  const float* __restrict__ rsumj,
                                                  float* __restrict__ colj) {
    const int b = blockIdx.x, p = threadIdx.x;
    const float pmv = (float)pm[b * L + p];
    const float* eb = E + b * (L * L);
    float acc = 0.f;
    for (int q = 0; q < L; ++q) {
        float mm = pmv * (float)qm[b * L + q];
        float x = eb[q * L + p] * mm;
        float inv = 1.0f / (rsumj[b * L + q] + EPS);
        acc += mm * __expf(x - rmaxj[b * L + q]) * inv;
    }
    colj[b * L + p] = acc;
}

__global__ __launch_bounds__(256) void k_colsum_i(const float* __restrict__ E,
                                                  const int* __restrict__ qm,
                                                  const int* __restrict__ pm,
                                                  const float* __restrict__ rmaxi,
                                                  const float* __restrict__ rsumi,
                                                  float* __restrict__ coli) {
    const int wid = threadIdx.x >> 6, lane = threadIdx.x & 63;
    const int row = blockIdx.x * 4 + wid;        // row = b*256 + q
    const int b = row >> 8, q = row & 255;
    const float qmv = (float)qm[b * L + q];
    const float* er = E + row * L;
    float acc = 0.f;
    #pragma unroll
    for (int i = 0; i < 4; ++i) {
        int pp = lane + 64 * i;
        float mm = qmv * (float)pm[b * L + pp];
        float x = er[pp] * mm;
        acc += mm * __expf(x - rmaxi[b * L + pp]) / (rsumi[b * L + pp] + EPS);
    }
    #pragma unroll
    for (int o = 32; o; o >>= 1) acc += __shfl_xor(acc, o);
    if (lane == 0) coli[row] = acc;
}

__global__ __launch_bounds__(256) void k_sums(const float* __restrict__ Q,
                                              const float* __restrict__ P,
                                              const float* __restrict__ colj,
                                              const float* __restrict__ coli,
                                              float* __restrict__ sumq,
                                              float* __restrict__ sump,
                                              float* __restrict__ sumbeta,
                                              float* __restrict__ sumalpha) {
    const int b = blockIdx.x >> 2;
    const int d = (blockIdx.x & 3) * 256 + threadIdx.x;
    float aq = 0.f, ap = 0.f, ab = 0.f, aa = 0.f;
    for (int l = 0; l < L; ++l) {
        float qv = Q[l * BD + b * D + d];
        float pv = P[l * BD + b * D + d];
        aq += qv; ap += pv;
        ab += colj[b * L + l] * pv;
        aa += coli[b * L + l] * qv;
    }
    sumq[b * D + d] = aq;  sump[b * D + d] = ap;
    sumbeta[b * D + d] = ab; sumalpha[b * D + d] = aa;
}

__global__ __launch_bounds__(256) void k_g(const float* __restrict__ WG,
                                           const float* __restrict__ WH,
                                           float* __restrict__ g1,
                                           float* __restrict__ g2) {
    const int k = blockIdx.x * 256 + threadIdx.x;   // 0..2047
    float a = 0.f, c = 0.f;
    for (int e = 0; e < D; ++e) {
        float w = WG[e * (2 * D) + k];
        a += w * WH[e];
        c += w * WH[D + e];
    }
    g1[k] = a; g2[k] = c;
}

__global__ __launch_bounds__(256) void k_final(const float* __restrict__ sumq,
                                               const float* __restrict__ sump,
                                               const float* __restrict__ sumbeta,
                                               const float* __restrict__ sumalpha,
                                               const float* __restrict__ g1,
                                               const float* __restrict__ g2,
                                               float* __restrict__ out) {
    const int b = blockIdx.x, t = threadIdx.x;
    float acc = 0.f;
    for (int d = t; d < D; d += 256) {
        acc += sumq[b * D + d] * g1[d] + sumbeta[b * D + d] * g1[D + d] +
               sump[b * D + d] * g2[d] + sumalpha[b * D + d] * g2[D + d];
    }
    #pragma unroll
    for (int o = 32; o; o >>= 1) acc += __shfl_xor(acc, o);
    __shared__ float red[4];
    const int wid = t >> 6, lane = t & 63;
    if (lane == 0) red[wid] = acc;
    __syncthreads();
    if (t == 0) out[b] = red[0] + red[1] + red[2] + red[3];
}

// ---------------------------------------------------------------------------
extern "C" void kernel_launch(void* const* d_in, const int* in_sizes, int n_in,
                              void* d_out, int out_size, void* d_ws, size_t ws_size,
                              hipStream_t stream) {
    const float* q  = (const float*)d_in[0];
    const float* p  = (const float*)d_in[1];
    const int*   qm = (const int*)d_in[2];
    const int*   pm = (const int*)d_in[3];
    const float* WF = (const float*)d_in[4];
    const float* WG = (const float*)d_in[5];
    const float* WH = (const float*)d_in[6];
    float* out = (float*)d_out;

    // Workspace layout (peak ~145.4 MB)
    char* wsb = (char*)d_ws;
    short* qh   = (short*)(wsb);                   // 32 MB  (later: ph)
    short* ql   = (short*)(wsb + (32l << 20));     // 32 MB  (later: pl)
    short* Th   = (short*)(wsb + (64l << 20));     // 32 MB
    short* Tl   = (short*)(wsb + (96l << 20));     // 32 MB
    short* WFth = (short*)(wsb + (128l << 20));    // 2 MB   (dead after gram)
    short* WFtl = (short*)(wsb + (130l << 20));    // 2 MB
    short* Gh   = (short*)(wsb + (132l << 20));    // 2 MB   (dead after qG)
    short* Gl   = (short*)(wsb + (134l << 20));    // 2 MB
    float* E    = (float*)(wsb + (128l << 20));    // 16 MB  (overlays WFt/G)
    float* st   = (float*)(wsb + (144l << 20));
    const int BL = B * L;
    float* rmj  = st;            float* rsj  = rmj + BL;
    float* rmi  = rsj + BL;      float* rsi  = rmi + BL;
    float* colj = rsi + BL;      float* coli = colj + BL;
    float* sumq = coli + BL;     float* sump = sumq + B * D;
    float* sumb = sump + B * D;  float* suma = sumb + B * D;
    float* g1   = suma + B * D;  float* g2   = g1 + 2 * D;

    // 1. q -> hi/lo bf16
    k_cvt<<<8192, 256, 0, stream>>>(q, qh, ql);
    // 2. WF -> transposed hi/lo bf16
    k_cvt_t<<<dim3(32, 32), 256, 0, stream>>>(WF, WFth, WFtl);
    // 3. G = WFt @ WFt^T (= WF^T WF), split-out hi/lo.  M=N=K=1024, grid 64
    k_gemm_nt<<<64, 256, 0, stream>>>(WFth, WFtl, 2048, 0, WFth, WFtl, 2048, 0,
                                      1024, 8, 64, 1, Gh, Gl, nullptr, 1024, 0);
    // 4. T = q @ G (G symmetric -> NT on G rows), split-out hi/lo. grid 1024
    k_gemm_nt<<<1024, 256, 0, stream>>>(qh, ql, 2048, 0, Gh, Gl, 2048, 0,
                                        1024, 8, 1024, 1, Th, Tl, nullptr, 1024, 0);
    // 5. p -> hi/lo bf16 (reuse q's region; q no longer needed in bf16 form)
    k_cvt<<<8192, 256, 0, stream>>>(p, qh, ql);
    // 6. E[b] = T_b @ P_b^T, fp32 out. grid 256 (2x2 x 64 batches)
    k_gemm_nt<<<256, 256, 0, stream>>>(Th, Tl, 64l * 2048, 2048, qh, ql, 64l * 2048, 2048,
                                       1024, 2, 4, 0, nullptr, nullptr, E, 256, 65536);
    // 7. softmax stats (both directions)
    k_rowstats_j<<<BL / 4, 256, 0, stream>>>(E, qm, pm, rmj, rsj);
    k_rowstats_i<<<B, 256, 0, stream>>>(E, qm, pm, rmi, rsi);
    // 8. column sums of softmax matrices
    k_colsum_j<<<B, 256, 0, stream>>>(E, qm, pm, rmj, rsj, colj);
    k_colsum_i<<<BL / 4, 256, 0, stream>>>(E, qm, pm, rmi, rsi, coli);
    // 9. per-batch sums over L
    k_sums<<<B * 4, 256, 0, stream>>>(q, p, colj, coli, sumq, sump, sumb, suma);
    // 10. folded WG/WH vectors
    k_g<<<(2 * D) / 256, 256, 0, stream>>>(WG, WH, g1, g2);
    // 11. final dot products
    k_final<<<B, 256, 0, stream>>>(sumq, sump, sumb, suma, g1, g2, out);
}

// Round 3
// 195.757 us; speedup vs baseline: 3.8631x; 1.9029x over previous
//
#include <hip/hip_runtime.h>

typedef _Float16 f16x8 __attribute__((ext_vector_type(8)));
using f32x4 = __attribute__((ext_vector_type(4))) float;

constexpr int B = 64, L = 256, D = 1024;
constexpr int BD = B * D;          // 65536
constexpr float EPS = 1e-6f;

__device__ __forceinline__ void gload_lds16(const void* g, void* l) {
    __builtin_amdgcn_global_load_lds((const __attribute__((address_space(1))) void*)g,
                                     (__attribute__((address_space(3))) void*)l,
                                     16, 0, 0);
}

// ---------------------------------------------------------------------------
// fp32 -> fp16, 8 elems/thread. grid*256*8 == n.
// ---------------------------------------------------------------------------
__global__ __launch_bounds__(256) void k_cvt(const float* __restrict__ x,
                                             short* __restrict__ y) {
    const int i = blockIdx.x * 256 + threadIdx.x;
    const float4* xp = (const float4*)x;
    float4 a = xp[2 * i], b = xp[2 * i + 1];
    float v[8] = {a.x, a.y, a.z, a.w, b.x, b.y, b.z, b.w};
    union { _Float16 h[8]; int4 q; } u;
    #pragma unroll
    for (int k = 0; k < 8; ++k) u.h[k] = (_Float16)v[k];
    ((int4*)y)[i] = u.q;
}

// ---------------------------------------------------------------------------
// WF [D][D] fp32 -> transposed fp16 (Y[k1][e] = WF[e][k1])
// ---------------------------------------------------------------------------
__global__ __launch_bounds__(256) void k_cvt_t(const float* __restrict__ X,
                                               short* __restrict__ Y) {
    __shared__ float tile[32][33];
    const int t = threadIdx.x;
    const int rt = blockIdx.y, ct = blockIdx.x;
    const int r = t >> 3, c4 = (t & 7) * 4;
    float4 v = *(const float4*)(X + (long)(rt * 32 + r) * D + ct * 32 + c4);
    tile[r][c4] = v.x; tile[r][c4 + 1] = v.y; tile[r][c4 + 2] = v.z; tile[r][c4 + 3] = v.w;
    __syncthreads();
    union { _Float16 h[4]; short4 s; } u;
    u.h[0] = (_Float16)tile[c4 + 0][r];
    u.h[1] = (_Float16)tile[c4 + 1][r];
    u.h[2] = (_Float16)tile[c4 + 2][r];
    u.h[3] = (_Float16)tile[c4 + 3][r];
    *(short4*)(Y + (long)(ct * 32 + r) * D + rt * 32 + c4) = u.s;
}

// ---------------------------------------------------------------------------
// fp16 NT GEMM: C = A @ B^T, both operands K-major. 128x128 tile, BK=32,
// 4 waves each 64x64 (4x4 frags of 16x16x32_f16). LDS 2 bufs x 16KB = 32KB.
// 2-phase prefetch, global_load_lds w=16, pre-swizzled source (0 conflicts, R2).
// MFMA operands SWAPPED (mfma(b,a,acc)) so acc reg-axis = output COLUMN ->
// vectorized short4/float4 epilogue stores.
// ---------------------------------------------------------------------------
__global__ __launch_bounds__(256, 4) void k_gemm16(
    const short* __restrict__ A, long strideA, long batchA,
    const short* __restrict__ Bm, long strideB, long batchB,
    int K, int bx, int per_batch, int f16_out,
    short* __restrict__ Ch, float* __restrict__ Cf, int ldC, long batchC)
{
    __shared__ __align__(16) short lds_s[16384];   // 32 KB
    const int t = threadIdx.x, lane = t & 63, w = t >> 6;
    const int wm = w >> 1, wn = w & 1;

    // XCD-bijective swizzle (grids divisible by 8)
    const int lin = blockIdx.x;
    const int chunk = gridDim.x >> 3;
    const int swz = (lin & 7) * chunk + (lin >> 3);
    const int z = swz / per_batch;
    const int r0 = swz % per_batch;
    const int mb = (r0 / bx) * 128, nb = (r0 % bx) * 128;

    // wave w stages 64 rows: w0:A[0:64] w1:A[64:128] w2:B[0:64] w3:B[64:128]
    const char* mat = (w < 2) ? ((const char*)A + batchA * z)
                              : ((const char*)Bm + batchB * z);
    const long rstride = (w < 2) ? strideA : strideB;
    const int row0 = (w < 2) ? mb : nb;
    const int half = (w & 1) * 64;
    const char* sp[4];
    #pragma unroll
    for (int i = 0; i < 4; ++i) {
        int tr = half + i * 16 + (lane >> 2);          // tile row 0..127
        int g = (lane & 3) ^ ((tr >> 1) & 3);          // inverse-swizzled granule
        sp[i] = mat + (long)(row0 + tr) * rstride + g * 16;
    }
    short* dst0 = lds_s + ((w >> 1) ? 4096 : 0) + (w & 1) * 2048;

    // swizzled fragment byte offsets within a 16KB buffer (A at 0, B at 8192)
    int aoff[4], boff[4];
    #pragma unroll
    for (int f = 0; f < 4; ++f) {
        int ra = wm * 64 + f * 16 + (lane & 15);
        aoff[f] = (ra * 4 + ((lane >> 4) ^ ((ra >> 1) & 3))) * 16;
        int rb = wn * 64 + f * 16 + (lane & 15);
        boff[f] = 8192 + (rb * 4 + ((lane >> 4) ^ ((rb >> 1) & 3))) * 16;
    }

    f32x4 acc[4][4] = {};
    const int NT = K >> 5;

    {   // prologue stage of buf 0
        #pragma unroll
        for (int i = 0; i < 4; ++i) gload_lds16(sp[i], dst0 + i * 512);
    }
    __syncthreads();

    int cur = 0;
    for (int kt = 0; kt < NT; ++kt) {
        if (kt + 1 < NT) {
            short* dst = dst0 + (cur ^ 1) * 8192;
            long ko = (long)(kt + 1) * 64;
            #pragma unroll
            for (int i = 0; i < 4; ++i) gload_lds16(sp[i] + ko, dst + i * 512);
        }
        const char* lb = (const char*)lds_s + cur * 16384;
        f16x8 a[4], b[4];
        #pragma unroll
        for (int f = 0; f < 4; ++f) {
            a[f] = *(const f16x8*)(lb + aoff[f]);
            b[f] = *(const f16x8*)(lb + boff[f]);
        }
        #pragma unroll
        for (int i = 0; i < 4; ++i)
            #pragma unroll
            for (int j = 0; j < 4; ++j)
                acc[i][j] = __builtin_amdgcn_mfma_f32_16x16x32_f16(b[j], a[i], acc[i][j], 0, 0, 0);
        __syncthreads();
        cur ^= 1;
    }

    // epilogue: swapped mapping -> C-row = lane&15, C-col = (lane>>4)*4 + reg
    const long zC = batchC * z;
    #pragma unroll
    for (int i = 0; i < 4; ++i)
        #pragma unroll
        for (int j = 0; j < 4; ++j) {
            int row = mb + wm * 64 + i * 16 + (lane & 15);
            int col = nb + wn * 64 + j * 16 + (lane >> 4) * 4;
            long idx = zC + (long)row * ldC + col;
            if (f16_out) {
                union { _Float16 h[4]; short4 s; } u;
                #pragma unroll
                for (int rr = 0; rr < 4; ++rr) u.h[rr] = (_Float16)acc[i][j][rr];
                *(short4*)(Ch + idx) = u.s;
            } else {
                float4 v = make_float4(acc[i][j][0], acc[i][j][1], acc[i][j][2], acc[i][j][3]);
                *(float4*)(Cf + idx) = v;
            }
        }
}

// ---------------------------------------------------------------------------
// Tiled softmax pass 1. Block = (qc, b): 32 q-rows x all 256 p.
// Computes: complete j-row stats in-block -> colj partials per p;
//           i-direction partial (max, sum) per p over this q-chunk.
// ---------------------------------------------------------------------------
__global__ __launch_bounds__(256) void k_pass1(const float* __restrict__ E,
                                               const int* __restrict__ qm,
                                               const int* __restrict__ pm,
                                               float* __restrict__ impart,
                                               float* __restrict__ ispart,
                                               float* __restrict__ cjpart) {
    const int qc = blockIdx.x, b = blockIdx.y;
    const int p = threadIdx.x, lane = p & 63, w = p >> 6;
    const int q0 = qc * 32;
    __shared__ float wred[32][4];
    __shared__ float rowmx[32], rowsm[32], qmv_s[32];
    if (p < 32) qmv_s[p] = (float)qm[b * L + q0 + p];
    __syncthreads();
    const float pmv = (float)pm[b * L + p];
    const float* eb = E + b * (L * L) + q0 * L + p;

    float xv[32];
    float im = -1e30f;
    // phase A: load, per-thread i-max, per-row max reduce
    #pragma unroll
    for (int r = 0; r < 32; ++r) {
        float mm = pmv * qmv_s[r];
        float x = eb[r * L] * mm;
        xv[r] = x;
        im = fmaxf(im, x);
        float v = x;
        #pragma unroll
        for (int o = 32; o; o >>= 1) v = fmaxf(v, __shfl_xor(v, o));
        if (lane == 0) wred[r][w] = v;
    }
    __syncthreads();
    if (p < 32) rowmx[p] = fmaxf(fmaxf(wred[p][0], wred[p][1]), fmaxf(wred[p][2], wred[p][3]));
    __syncthreads();
    // phase B: row sums + per-thread i-sum (im now final for this chunk)
    float is = 0.f;
    #pragma unroll
    for (int r = 0; r < 32; ++r) {
        float mm = pmv * qmv_s[r];
        is += mm * __expf(xv[r] - im);
        float v = mm * __expf(xv[r] - rowmx[r]);
        #pragma unroll
        for (int o = 32; o; o >>= 1) v += __shfl_xor(v, o);
        if (lane == 0) wred[r][w] = v;
    }
    __syncthreads();
    if (p < 32) rowsm[p] = wred[p][0] + wred[p][1] + wred[p][2] + wred[p][3];
    __syncthreads();
    // phase C: colj partial
    float cj = 0.f;
    #pragma unroll
    for (int r = 0; r < 32; ++r) {
        float mm = pmv * qmv_s[r];
        cj += mm * __expf(xv[r] - rowmx[r]) / (rowsm[r] + EPS);
    }
    const int o = (b * 8 + qc) * 256 + p;
    impart[o] = im; ispart[o] = is; cjpart[o] = cj;
}

// combine 8 chunk-partials -> rmi, rsi, colj.  grid B, 256 threads (p).
__global__ __launch_bounds__(256) void k_combine(const float* __restrict__ impart,
                                                 const float* __restrict__ ispart,
                                                 const float* __restrict__ cjpart,
                                                 float* __restrict__ rmi,
                                                 float* __restrict__ rsi,
                                                 float* __restrict__ colj) {
    const int b = blockIdx.x, p = threadIdx.x;
    const int base = b * 8 * 256 + p;
    float m = -1e30f, s = 0.f, c = 0.f;
    #pragma unroll
    for (int k = 0; k < 8; ++k) m = fmaxf(m, impart[base + k * 256]);
    #pragma unroll
    for (int k = 0; k < 8; ++k) {
        s += ispart[base + k * 256] * __expf(impart[base + k * 256] - m);
        c += cjpart[base + k * 256];
    }
    rmi[b * L + p] = m; rsi[b * L + p] = s; colj[b * L + p] = c;
}

// colsum_i[b,q] = sum_p softmax_i[b,p,q]. One wave per (b,q) row.
__global__ __launch_bounds__(256) void k_colsum_i(const float* __restrict__ E,
                                                  const int* __restrict__ qm,
                                                  const int* __restrict__ pm,
                                                  const float* __restrict__ rmaxi,
                                                  const float* __restrict__ rsumi,
                                                  float* __restrict__ coli) {
    const int wid = threadIdx.x >> 6, lane = threadIdx.x & 63;
    const int row = blockIdx.x * 4 + wid;        // row = b*256 + q
    const int b = row >> 8;
    const float qmv = (float)qm[row];
    const float* er = E + row * L;
    float acc = 0.f;
    #pragma unroll
    for (int i = 0; i < 4; ++i) {
        int pp = lane + 64 * i;
        float mm = qmv * (float)pm[b * L + pp];
        float x = er[pp] * mm;
        acc += mm * __expf(x - rmaxi[b * L + pp]) / (rsumi[b * L + pp] + EPS);
    }
    #pragma unroll
    for (int o = 32; o; o >>= 1) acc += __shfl_xor(acc, o);
    if (lane == 0) coli[row] = acc;
}

// per-batch sums over L (reads fp16 copies of q,p).
__global__ __launch_bounds__(256) void k_sums(const short* __restrict__ Q16,
                                              const short* __restrict__ P16,
                                              const float* __restrict__ colj,
                                              const float* __restrict__ coli,
                                              float* __restrict__ sumq,
                                              float* __restrict__ sump,
                                              float* __restrict__ sumbeta,
                                              float* __restrict__ sumalpha) {
    const int b = blockIdx.x >> 2;
    const int d = (blockIdx.x & 3) * 256 + threadIdx.x;
    const _Float16* Q = (const _Float16*)Q16;
    const _Float16* P = (const _Float16*)P16;
    float aq = 0.f, ap = 0.f, ab = 0.f, aa = 0.f;
    for (int l = 0; l < L; ++l) {
        float qv = (float)Q[(long)l * BD + b * D + d];
        float pv = (float)P[(long)l * BD + b * D + d];
        aq += qv; ap += pv;
        ab += colj[b * L + l] * pv;
        aa += coli[b * L + l] * qv;
    }
    sumq[b * D + d] = aq;  sump[b * D + d] = ap;
    sumbeta[b * D + d] = ab; sumalpha[b * D + d] = aa;
}

// gp1/gp2 partials over e-chunks of 128. grid (8 kc, 8 ec).
__global__ __launch_bounds__(256) void k_gpart(const float* __restrict__ WG,
                                               const float* __restrict__ WH,
                                               float* __restrict__ gp1,
                                               float* __restrict__ gp2) {
    const int k = blockIdx.x * 256 + threadIdx.x;   // 0..2047
    const int e0 = blockIdx.y * 128;
    float a = 0.f, c = 0.f;
    for (int e = 0; e < 128; ++e) {
        float w = WG[(long)(e0 + e) * (2 * D) + k];
        a += w * WH[e0 + e];
        c += w * WH[D + e0 + e];
    }
    gp1[blockIdx.y * 2048 + k] = a; gp2[blockIdx.y * 2048 + k] = c;
}

__global__ __launch_bounds__(256) void k_final(const float* __restrict__ sumq,
                                               const float* __restrict__ sump,
                                               const float* __restrict__ sumbeta,
                                               const float* __restrict__ sumalpha,
                                               const float* __restrict__ gp1,
                                               const float* __restrict__ gp2,
                                               float* __restrict__ out) {
    const int b = blockIdx.x, t = threadIdx.x;
    float acc = 0.f;
    for (int d = t; d < D; d += 256) {
        float g1d = 0.f, g1D = 0.f, g2d = 0.f, g2D = 0.f;
        #pragma unroll
        for (int ec = 0; ec < 8; ++ec) {
            g1d += gp1[ec * 2048 + d];     g1D += gp1[ec * 2048 + D + d];
            g2d += gp2[ec * 2048 + d];     g2D += gp2[ec * 2048 + D + d];
        }
        acc += sumq[b * D + d] * g1d + sumbeta[b * D + d] * g1D +
               sump[b * D + d] * g2d + sumalpha[b * D + d] * g2D;
    }
    #pragma unroll
    for (int o = 32; o; o >>= 1) acc += __shfl_xor(acc, o);
    __shared__ float red[4];
    const int wid = t >> 6, lane = t & 63;
    if (lane == 0) red[wid] = acc;
    __syncthreads();
    if (t == 0) out[b] = red[0] + red[1] + red[2] + red[3];
}

// ---------------------------------------------------------------------------
extern "C" void kernel_launch(void* const* d_in, const int* in_sizes, int n_in,
                              void* d_out, int out_size, void* d_ws, size_t ws_size,
                              hipStream_t stream) {
    const float* q  = (const float*)d_in[0];
    const float* p  = (const float*)d_in[1];
    const int*   qm = (const int*)d_in[2];
    const int*   pm = (const int*)d_in[3];
    const float* WF = (const float*)d_in[4];
    const float* WG = (const float*)d_in[5];
    const float* WH = (const float*)d_in[6];
    float* out = (float*)d_out;

    // Workspace layout (~119 MB)
    char* wsb = (char*)d_ws;
    short* q16   = (short*)(wsb);                   // 32 MB
    short* p16   = (short*)(wsb + (32l << 20));     // 32 MB
    short* T16   = (short*)(wsb + (64l << 20));     // 32 MB
    short* WFt16 = (short*)(wsb + (96l << 20));     // 2 MB
    short* G16   = (short*)(wsb + (98l << 20));     // 2 MB
    float* E     = (float*)(wsb + (100l << 20));    // 16 MB
    float* st    = (float*)(wsb + (116l << 20));
    const int BL = B * L;
    float* impart = st;                 float* ispart = impart + B * 8 * 256;
    float* cjpart = ispart + B * 8 * 256;
    float* rmi  = cjpart + B * 8 * 256; float* rsi  = rmi + BL;
    float* colj = rsi + BL;             float* coli = colj + BL;
    float* sumq = coli + BL;            float* sump = sumq + B * D;
    float* sumb = sump + B * D;         float* suma = sumb + B * D;
    float* gp1  = suma + B * D;         float* gp2  = gp1 + 8 * 2048;

    // conversions
    k_cvt<<<8192, 256, 0, stream>>>(q, q16);
    k_cvt<<<8192, 256, 0, stream>>>(p, p16);
    k_cvt_t<<<dim3(32, 32), 256, 0, stream>>>(WF, WFt16);
    // G = WFt @ WFt^T (= WF^T WF), f16 out. grid 64
    k_gemm16<<<64, 256, 0, stream>>>(WFt16, 2048, 0, WFt16, 2048, 0,
                                     1024, 8, 64, 1, G16, nullptr, 1024, 0);
    // T = q @ G (G symmetric -> NT on G rows), f16 out. grid 1024
    k_gemm16<<<1024, 256, 0, stream>>>(q16, 2048, 0, G16, 2048, 0,
                                       1024, 8, 1024, 1, T16, nullptr, 1024, 0);
    // E[b] = T_b @ p_b^T, f32 out. grid 256
    k_gemm16<<<256, 256, 0, stream>>>(T16, 64l * 2048, 2048, p16, 64l * 2048, 2048,
                                      1024, 2, 4, 0, nullptr, E, 256, 65536);
    // softmax: tiled pass1 + combine + coli
    k_pass1<<<dim3(8, B), 256, 0, stream>>>(E, qm, pm, impart, ispart, cjpart);
    k_combine<<<B, 256, 0, stream>>>(impart, ispart, cjpart, rmi, rsi, colj);
    k_colsum_i<<<BL / 4, 256, 0, stream>>>(E, qm, pm, rmi, rsi, coli);
    // per-batch sums over L (fp16 q/p)
    k_sums<<<B * 4, 256, 0, stream>>>(q16, p16, colj, coli, sumq, sump, sumb, suma);
    // folded WG/WH vectors (partials) + final
    k_gpart<<<dim3(8, 8), 256, 0, stream>>>(WG, WH, gp1, gp2);
    k_final<<<B, 256, 0, stream>>>(sumq, sump, sumb, suma, gp1, gp2, out);
}

// Round 5
// 183.081 us; speedup vs baseline: 4.1306x; 1.0692x over previous
//
#include <hip/hip_runtime.h>

typedef _Float16 f16x8 __attribute__((ext_vector_type(8)));
using f32x4 = __attribute__((ext_vector_type(4))) float;

constexpr int B = 64, L = 256, D = 1024;
constexpr int BD = B * D;          // 65536
constexpr float EPS = 1e-6f;

__device__ __forceinline__ void gload_lds16(const void* g, void* l) {
    __builtin_amdgcn_global_load_lds((const __attribute__((address_space(1))) void*)g,
                                     (__attribute__((address_space(3))) void*)l,
                                     16, 0, 0);
}

// ---------------------------------------------------------------------------
// fp32 -> fp16 for q and p in one kernel. 8 elems/thread.
// ---------------------------------------------------------------------------
__global__ __launch_bounds__(256) void k_cvt2(const float* __restrict__ q,
                                              const float* __restrict__ p,
                                              short* __restrict__ q16,
                                              short* __restrict__ p16) {
    const int i = blockIdx.x * 256 + threadIdx.x;
    constexpr int HALF = (L * B * D) / 8;       // 2097152
    const float* src; short* dst; int j;
    if (i < HALF) { src = q; dst = q16; j = i; }
    else          { src = p; dst = p16; j = i - HALF; }
    float4 a = ((const float4*)src)[2 * j], b = ((const float4*)src)[2 * j + 1];
    float v[8] = {a.x, a.y, a.z, a.w, b.x, b.y, b.z, b.w};
    union { _Float16 h[8]; int4 q4; } u;
    #pragma unroll
    for (int k = 0; k < 8; ++k) u.h[k] = (_Float16)v[k];
    ((int4*)dst)[j] = u.q4;
}

// ---------------------------------------------------------------------------
// WF [D][D] fp32 -> transposed fp16 (Y[k1][e] = WF[e][k1])
// ---------------------------------------------------------------------------
__global__ __launch_bounds__(256) void k_cvt_t(const float* __restrict__ X,
                                               short* __restrict__ Y) {
    __shared__ float tile[32][33];
    const int t = threadIdx.x;
    const int rt = blockIdx.y, ct = blockIdx.x;
    const int r = t >> 3, c4 = (t & 7) * 4;
    float4 v = *(const float4*)(X + (long)(rt * 32 + r) * D + ct * 32 + c4);
    tile[r][c4] = v.x; tile[r][c4 + 1] = v.y; tile[r][c4 + 2] = v.z; tile[r][c4 + 3] = v.w;
    __syncthreads();
    union { _Float16 h[4]; short4 s; } u;
    u.h[0] = (_Float16)tile[c4 + 0][r];
    u.h[1] = (_Float16)tile[c4 + 1][r];
    u.h[2] = (_Float16)tile[c4 + 2][r];
    u.h[3] = (_Float16)tile[c4 + 3][r];
    *(short4*)(Y + (long)(ct * 32 + r) * D + rt * 32 + c4) = u.s;
}

// ---------------------------------------------------------------------------
// fp16 NT GEMM, wave-tile (MR*16)x64. BM=WM*MR*16, BN=WN*64, BK=32.
// Counted-wait pipeline: per K-step {vmcnt(0) on loads issued ONE FULL STEP
// ago -> raw barrier -> issue next stage -> ds_read -> MFMA}. The wait never
// covers same-step loads, so HBM latency hides under the MFMA phase.
// Staging: global_load_lds w=16, linear LDS dest, pre-swizzled source
// granule lg = sg ^ ((row>>1)&3)  (0 bank conflicts, verified R2/R3).
// MFMA operands swapped -> acc reg-axis = output column -> vector stores.
// ---------------------------------------------------------------------------
template <int WM, int WN, int MR>
__global__ __launch_bounds__(WM * WN * 64) void k_gemm(
    const short* __restrict__ A, long sA, long bA,
    const short* __restrict__ Bm, long sB, long bB,
    int K, int bx, int per_batch, int f16_out,
    short* __restrict__ Ch, float* __restrict__ Cf, int ldC, long batchC)
{
    constexpr int BM = WM * MR * 16, BN = WN * 64;
    constexpr int T = WM * WN * 64;
    constexpr int TILEB = (BM + BN) * 64;        // bytes per K-step buffer
    constexpr int ROUNDS = TILEB / (T * 16);
    __shared__ __align__(16) char lds[2 * TILEB];

    const int t = threadIdx.x, lane = t & 63, w = t >> 6;
    const int wm = w / WN, wn = w % WN;

    // XCD-bijective swizzle (grids divisible by 8)
    const int lin = blockIdx.x;
    const int chunk = gridDim.x >> 3;
    const int swz = (lin & 7) * chunk + (lin >> 3);
    const int z = swz / per_batch;
    const int r0 = swz % per_batch;
    const int mb = (r0 / bx) * BM, nb = (r0 % bx) * BN;

    const char* Ab = (const char*)A + bA * z;
    const char* Bb = (const char*)Bm + bB * z;

    // stage source pointers (pre-swizzled granule)
    const char* sp[ROUNDS];
    #pragma unroll
    for (int r = 0; r < ROUNDS; ++r) {
        int g = r * T + t;
        int row = g >> 2, sg = g & 3;
        int lg = sg ^ ((row >> 1) & 3);
        if (row < BM) sp[r] = Ab + (long)(mb + row) * sA + lg * 16;
        else          sp[r] = Bb + (long)(nb + row - BM) * sB + lg * 16;
    }

    // fragment byte offsets (swizzled reads)
    int aoff[MR], boff[4];
    #pragma unroll
    for (int i = 0; i < MR; ++i) {
        int ra = wm * (MR * 16) + i * 16 + (lane & 15);
        aoff[i] = ra * 64 + (((lane >> 4) ^ ((ra >> 1) & 3))) * 16;
    }
    #pragma unroll
    for (int j = 0; j < 4; ++j) {
        int rb = wn * 64 + j * 16 + (lane & 15);
        boff[j] = BM * 64 + rb * 64 + (((lane >> 4) ^ ((rb >> 1) & 3))) * 16;
    }

    f32x4 acc[MR][4] = {};
    const int NT = K >> 5;

    {   // prologue: stage K-tile 0 into buf 0
        #pragma unroll
        for (int r = 0; r < ROUNDS; ++r)
            gload_lds16(sp[r], lds + (r * T + t) * 16);
    }

    int cur = 0;
    for (int kt = 0; kt < NT; ++kt) {
        // wait for buf[cur]'s stage (issued one full step ago), then sync
        asm volatile("s_waitcnt vmcnt(0)" ::: "memory");
        __builtin_amdgcn_sched_barrier(0);
        __builtin_amdgcn_s_barrier();
        __builtin_amdgcn_sched_barrier(0);
        // issue next-tile stage into buf[cur^1] (all waves past barrier ->
        // everyone finished reading buf[cur^1] last step)
        if (kt + 1 < NT) {
            long kb = (long)(kt + 1) * 64;
            char* dstb = lds + (cur ^ 1) * TILEB;
            #pragma unroll
            for (int r = 0; r < ROUNDS; ++r)
                gload_lds16(sp[r] + kb, dstb + (r * T + t) * 16);
        }
        __builtin_amdgcn_sched_barrier(0);
        // compute from buf[cur]
        const char* lb = lds + cur * TILEB;
        f16x8 fb[4], fa[MR];
        #pragma unroll
        for (int j = 0; j < 4; ++j) fb[j] = *(const f16x8*)(lb + boff[j]);
        #pragma unroll
        for (int i = 0; i < MR; ++i) fa[i] = *(const f16x8*)(lb + aoff[i]);
        #pragma unroll
        for (int i = 0; i < MR; ++i)
            #pragma unroll
            for (int j = 0; j < 4; ++j)
                acc[i][j] = __builtin_amdgcn_mfma_f32_16x16x32_f16(fb[j], fa[i], acc[i][j], 0, 0, 0);
        cur ^= 1;
    }

    // epilogue: swapped mapping -> C-row = lane&15, C-col = (lane>>4)*4 + reg
    const long zC = batchC * z;
    #pragma unroll
    for (int i = 0; i < MR; ++i)
        #pragma unroll
        for (int j = 0; j < 4; ++j) {
            int row = mb + wm * (MR * 16) + i * 16 + (lane & 15);
            int col = nb + wn * 64 + j * 16 + (lane >> 4) * 4;
            long idx = zC + (long)row * ldC + col;
            if (f16_out) {
                union { _Float16 h[4]; short4 s; } u;
                #pragma unroll
                for (int rr = 0; rr < 4; ++rr) u.h[rr] = (_Float16)acc[i][j][rr];
                *(short4*)(Ch + idx) = u.s;
            } else {
                float4 v = make_float4(acc[i][j][0], acc[i][j][1], acc[i][j][2], acc[i][j][3]);
                *(float4*)(Cf + idx) = v;
            }
        }
}

// ---------------------------------------------------------------------------
// fold 4 f32 gram partials -> f16 G
// ---------------------------------------------------------------------------
__global__ __launch_bounds__(256) void k_fold_g(const float* __restrict__ Gp,
                                                short* __restrict__ G16) {
    const int i = blockIdx.x * 256 + threadIdx.x;    // float4 index
    constexpr int N4 = (1 << 20) / 4;
    const float4* g = (const float4*)Gp;
    float4 v0 = g[i], v1 = g[N4 + i], v2 = g[2 * N4 + i], v3 = g[3 * N4 + i];
    union { _Float16 h[4]; short4 s; } u;
    u.h[0] = (_Float16)(v0.x + v1.x + v2.x + v3.x);
    u.h[1] = (_Float16)(v0.y + v1.y + v2.y + v3.y);
    u.h[2] = (_Float16)(v0.z + v1.z + v2.z + v3.z);
    u.h[3] = (_Float16)(v0.w + v1.w + v2.w + v3.w);
    ((short4*)G16)[i] = u.s;
}

// ---------------------------------------------------------------------------
// Tiled softmax pass 1 (unchanged — verified R3)
// ---------------------------------------------------------------------------
__global__ __launch_bounds__(256) void k_pass1(const float* __restrict__ E,
                                               const int* __restrict__ qm,
                                               const int* __restrict__ pm,
                                               float* __restrict__ impart,
                                               float* __restrict__ ispart,
                                               float* __restrict__ cjpart) {
    const int qc = blockIdx.x, b = blockIdx.y;
    const int p = threadIdx.x, lane = p & 63, w = p >> 6;
    const int q0 = qc * 32;
    __shared__ float wred[32][4];
    __shared__ float rowmx[32], rowsm[32], qmv_s[32];
    if (p < 32) qmv_s[p] = (float)qm[b * L + q0 + p];
    __syncthreads();
    const float pmv = (float)pm[b * L + p];
    const float* eb = E + b * (L * L) + q0 * L + p;

    float xv[32];
    float im = -1e30f;
    #pragma unroll
    for (int r = 0; r < 32; ++r) {
        float mm = pmv * qmv_s[r];
        float x = eb[r * L] * mm;
        xv[r] = x;
        im = fmaxf(im, x);
        float v = x;
        #pragma unroll
        for (int o = 32; o; o >>= 1) v = fmaxf(v, __shfl_xor(v, o));
        if (lane == 0) wred[r][w] = v;
    }
    __syncthreads();
    if (p < 32) rowmx[p] = fmaxf(fmaxf(wred[p][0], wred[p][1]), fmaxf(wred[p][2], wred[p][3]));
    __syncthreads();
    float is = 0.f;
    #pragma unroll
    for (int r = 0; r < 32; ++r) {
        float mm = pmv * qmv_s[r];
        is += mm * __expf(xv[r] - im);
        float v = mm * __expf(xv[r] - rowmx[r]);
        #pragma unroll
        for (int o = 32; o; o >>= 1) v += __shfl_xor(v, o);
        if (lane == 0) wred[r][w] = v;
    }
    __syncthreads();
    if (p < 32) rowsm[p] = wred[p][0] + wred[p][1] + wred[p][2] + wred[p][3];
    __syncthreads();
    float cj = 0.f;
    #pragma unroll
    for (int r = 0; r < 32; ++r) {
        float mm = pmv * qmv_s[r];
        cj += mm * __expf(xv[r] - rowmx[r]) / (rowsm[r] + EPS);
    }
    const int o = (b * 8 + qc) * 256 + p;
    impart[o] = im; ispart[o] = is; cjpart[o] = cj;
}

__global__ __launch_bounds__(256) void k_combine(const float* __restrict__ impart,
                                                 const float* __restrict__ ispart,
                                                 const float* __restrict__ cjpart,
                                                 float* __restrict__ rmi,
                                                 float* __restrict__ rsi,
                                                 float* __restrict__ colj) {
    const int b = blockIdx.x, p = threadIdx.x;
    const int base = b * 8 * 256 + p;
    float m = -1e30f, s = 0.f, c = 0.f;
    #pragma unroll
    for (int k = 0; k < 8; ++k) m = fmaxf(m, impart[base + k * 256]);
    #pragma unroll
    for (int k = 0; k < 8; ++k) {
        s += ispart[base + k * 256] * __expf(impart[base + k * 256] - m);
        c += cjpart[base + k * 256];
    }
    rmi[b * L + p] = m; rsi[b * L + p] = s; colj[b * L + p] = c;
}

__global__ __launch_bounds__(256) void k_colsum_i(const float* __restrict__ E,
                                                  const int* __restrict__ qm,
                                                  const int* __restrict__ pm,
                                                  const float* __restrict__ rmaxi,
                                                  const float* __restrict__ rsumi,
                                                  float* __restrict__ coli) {
    const int wid = threadIdx.x >> 6, lane = threadIdx.x & 63;
    const int row = blockIdx.x * 4 + wid;        // row = b*256 + q
    const int b = row >> 8;
    const float qmv = (float)qm[row];
    const float* er = E + row * L;
    float acc = 0.f;
    #pragma unroll
    for (int i = 0; i < 4; ++i) {
        int pp = lane + 64 * i;
        float mm = qmv * (float)pm[b * L + pp];
        float x = er[pp] * mm;
        acc += mm * __expf(x - rmaxi[b * L + pp]) / (rsumi[b * L + pp] + EPS);
    }
    #pragma unroll
    for (int o = 32; o; o >>= 1) acc += __shfl_xor(acc, o);
    if (lane == 0) coli[row] = acc;
}

// ---------------------------------------------------------------------------
// per-batch sums over an l-chunk of 64 (vectorized int4 = 8 f16 per load).
// ---------------------------------------------------------------------------
__global__ __launch_bounds__(128) void k_sums2(const short* __restrict__ Q16,
                                               const short* __restrict__ P16,
                                               const float* __restrict__ colj,
                                               const float* __restrict__ coli,
                                               float* __restrict__ pq,
                                               float* __restrict__ pp,
                                               float* __restrict__ pb,
                                               float* __restrict__ pa) {
    const int c = blockIdx.x, b = blockIdx.y, t = threadIdx.x;
    const int d0 = t * 8;
    float aq[8] = {}, ap[8] = {}, ab[8] = {}, aa[8] = {};
    for (int l = c * 64; l < c * 64 + 64; ++l) {
        union { int4 v; _Float16 h[8]; } uq, up;
        uq.v = *(const int4*)(Q16 + (long)l * BD + b * D + d0);
        up.v = *(const int4*)(P16 + (long)l * BD + b * D + d0);
        float cj = colj[b * L + l], ci = coli[b * L + l];
        #pragma unroll
        for (int k = 0; k < 8; ++k) {
            float qf = (float)uq.h[k], pf = (float)up.h[k];
            aq[k] += qf; ap[k] += pf; ab[k] += cj * pf; aa[k] += ci * qf;
        }
    }
    const long o = ((long)c * B + b) * D + d0;
    *(float4*)(pq + o) = make_float4(aq[0], aq[1], aq[2], aq[3]);
    *(float4*)(pq + o + 4) = make_float4(aq[4], aq[5], aq[6], aq[7]);
    *(float4*)(pp + o) = make_float4(ap[0], ap[1], ap[2], ap[3]);
    *(float4*)(pp + o + 4) = make_float4(ap[4], ap[5], ap[6], ap[7]);
    *(float4*)(pb + o) = make_float4(ab[0], ab[1], ab[2], ab[3]);
    *(float4*)(pb + o + 4) = make_float4(ab[4], ab[5], ab[6], ab[7]);
    *(float4*)(pa + o) = make_float4(aa[0], aa[1], aa[2], aa[3]);
    *(float4*)(pa + o + 4) = make_float4(aa[4], aa[5], aa[6], aa[7]);
}

__global__ __launch_bounds__(256) void k_gpart(const float* __restrict__ WG,
                                               const float* __restrict__ WH,
                                               float* __restrict__ gp1,
                                               float* __restrict__ gp2) {
    const int k = blockIdx.x * 256 + threadIdx.x;   // 0..2047
    const int e0 = blockIdx.y * 128;
    float a = 0.f, c = 0.f;
    for (int e = 0; e < 128; ++e) {
        float w = WG[(long)(e0 + e) * (2 * D) + k];
        a += w * WH[e0 + e];
        c += w * WH[D + e0 + e];
    }
    gp1[blockIdx.y * 2048 + k] = a; gp2[blockIdx.y * 2048 + k] = c;
}

__global__ __launch_bounds__(256) void k_final2(const float* __restrict__ pq,
                                                const float* __restrict__ pp,
                                                const float* __restrict__ pb,
                                                const float* __restrict__ pa,
                                                const float* __restrict__ gp1,
                                                const float* __restrict__ gp2,
                                                float* __restrict__ out) {
    const int b = blockIdx.x, t = threadIdx.x;
    float acc = 0.f;
    for (int d = t; d < D; d += 256) {
        float sq = 0.f, sp_ = 0.f, sb = 0.f, sa = 0.f;
        #pragma unroll
        for (int c2 = 0; c2 < 4; ++c2) {
            long o = ((long)c2 * B + b) * D + d;
            sq += pq[o]; sp_ += pp[o]; sb += pb[o]; sa += pa[o];
        }
        float g1d = 0.f, g1D = 0.f, g2d = 0.f, g2D = 0.f;
        #pragma unroll
        for (int ec = 0; ec < 8; ++ec) {
            g1d += gp1[ec * 2048 + d];     g1D += gp1[ec * 2048 + D + d];
            g2d += gp2[ec * 2048 + d];     g2D += gp2[ec * 2048 + D + d];
        }
        acc += sq * g1d + sb * g1D + sp_ * g2d + sa * g2D;
    }
    #pragma unroll
    for (int o = 32; o; o >>= 1) acc += __shfl_xor(acc, o);
    __shared__ float red[4];
    const int wid = t >> 6, lane = t & 63;
    if (lane == 0) red[wid] = acc;
    __syncthreads();
    if (t == 0) out[b] = red[0] + red[1] + red[2] + red[3];
}

// ---------------------------------------------------------------------------
extern "C" void kernel_launch(void* const* d_in, const int* in_sizes, int n_in,
                              void* d_out, int out_size, void* d_ws, size_t ws_size,
                              hipStream_t stream) {
    const float* q  = (const float*)d_in[0];
    const float* p  = (const float*)d_in[1];
    const int*   qm = (const int*)d_in[2];
    const int*   pm = (const int*)d_in[3];
    const float* WF = (const float*)d_in[4];
    const float* WG = (const float*)d_in[5];
    const float* WH = (const float*)d_in[6];
    float* out = (float*)d_out;

    // Workspace layout (~122 MB)
    char* wsb = (char*)d_ws;
    short* q16   = (short*)(wsb);                   // 32 MB
    short* p16   = (short*)(wsb + (32l << 20));     // 32 MB
    short* T16   = (short*)(wsb + (64l << 20));     // 32 MB
    short* WFt16 = (short*)(wsb + (96l << 20));     // 2 MB
    short* G16   = (short*)(wsb + (98l << 20));     // 2 MB
    float* Gp    = (float*)(wsb + (100l << 20));    // 16 MB (dead after fold)
    float* E     = (float*)(wsb + (100l << 20));    // 16 MB (overlays Gp)
    float* st    = (float*)(wsb + (116l << 20));
    const int BL = B * L;
    float* impart = st;                  float* ispart = impart + B * 8 * 256;
    float* cjpart = ispart + B * 8 * 256;
    float* rmi  = cjpart + B * 8 * 256;  float* rsi  = rmi + BL;
    float* colj = rsi + BL;              float* coli = colj + BL;
    float* pq   = coli + BL;             float* pp   = pq + 4 * BD;
    float* pb   = pp + 4 * BD;           float* pa   = pb + 4 * BD;
    float* gp1  = pa + 4 * BD;           float* gp2  = gp1 + 8 * 2048;

    // conversions
    k_cvt2<<<16384, 256, 0, stream>>>(q, p, q16, p16);
    k_cvt_t<<<dim3(32, 32), 256, 0, stream>>>(WF, WFt16);
    // gram partials: K-split 4 (z = K-chunk of 256), 128x128 block tiles,
    // per chunk 8x8 tiles -> per_batch 64, grid 256.  (R4 bug: was <1,2,4>)
    k_gemm<2, 2, 4><<<256, 256, 0, stream>>>(WFt16, 2048, 512, WFt16, 2048, 512,
                                             256, 8, 64, 0, nullptr, Gp, 1024, 1l << 20);
    k_fold_g<<<1024, 256, 0, stream>>>(Gp, G16);
    // T = q @ G (G symmetric -> NT on G rows), 256x256 tiles, grid 256
    k_gemm<2, 4, 8><<<256, 512, 0, stream>>>(q16, 2048, 0, G16, 2048, 0,
                                             1024, 4, 256, 1, T16, nullptr, 1024, 0);
    // E[b] = T_b @ p_b^T, 128x128 block tiles, 2x2 per batch, grid 256
    k_gemm<2, 2, 4><<<256, 256, 0, stream>>>(T16, 64l * 2048, 2048, p16, 64l * 2048, 2048,
                                             1024, 2, 4, 0, nullptr, E, 256, 65536);
    // softmax
    k_pass1<<<dim3(8, B), 256, 0, stream>>>(E, qm, pm, impart, ispart, cjpart);
    k_combine<<<B, 256, 0, stream>>>(impart, ispart, cjpart, rmi, rsi, colj);
    k_colsum_i<<<BL / 4, 256, 0, stream>>>(E, qm, pm, rmi, rsi, coli);
    // per-batch sums (vectorized, l-chunked)
    k_sums2<<<dim3(4, B), 128, 0, stream>>>(q16, p16, colj, coli, pq, pp, pb, pa);
    // folded WG/WH vectors (partials) + final
    k_gpart<<<dim3(8, 8), 256, 0, stream>>>(WG, WH, gp1, gp2);
    k_final2<<<B, 256, 0, stream>>>(pq, pp, pb, pa, gp1, gp2, out);
}